// Round 6
// baseline (362.313 us; speedup 1.0000x reference)
//
#include <hip/hip_runtime.h>
#include <stdint.h>

// B=4096 rows, S=8192 fp32 scores. Per row: k = seqlen/16+1, mean of top-k of
// first seqlen entries, sigmoid, BCE vs label, mean over rows -> scalar.
//
// Round 6: one-pass threshold filter. k/n ~= 1/16 always, so the kth largest
// is near the 93.75th pct of N(0,1). Per row compute conservative t0 with
// P(count(x>=t0) >= k) ~ 1-1e-12; single sweep spills only x>=t0 (~8%) into
// LDS + 256-bin hist of spilled; shuffle suffix-scan finds boundary bin;
// exact tie-aware rank among spilled (== global rank, since all non-spilled
// are < t0 <= kth value). Exact block-uniform fallback (2-pass from global)
// if the filter under/overflows. ~125us of dur_us is harness reset traffic.

#define SLEN 8192
#define BLK 256
#define NWAVE (BLK / 64)
#define NB 256                 // bins over [-6, 6); 1 bin per thread
#define CAP 2048
#define LOV (-6.0f)
#define SCALE (NB / 12.0f)

__device__ __forceinline__ int bin_of(float x) {
  int b = (int)((x - LOV) * SCALE);   // monotone non-decreasing in x
  return b < 0 ? 0 : (b > NB - 1 ? NB - 1 : b);
}

// Inverse upper-tail normal quantile, biased low (conservative).
// Hastings rational approx, |err| < ~5e-3, valid for p in (0, 0.5].
__device__ __forceinline__ float inv_q(float p) {
  float t = sqrtf(-2.0f * logf(p));
  return t - (2.30753f + 0.27061f * t) /
                 (1.0f + 0.99229f * t + 0.04481f * t * t) -
         0.03f;
}

__global__ __launch_bounds__(BLK, 8) void topk_bce_rows(
    const float* __restrict__ scores, const float* __restrict__ label,
    const int* __restrict__ seqlen, float* __restrict__ rowterm) {
  __shared__ float cand[CAP];        // 8 KB spill buffer
  __shared__ uint32_t hist[NB];      // 1 KB
  __shared__ uint32_t wtot[NWAVE];
  __shared__ uint32_t selBin, selAbove;
  __shared__ int ccount;
  __shared__ float redbuf[NWAVE];

  const int row = blockIdx.x;
  const int tid = threadIdx.x;
  const int lane = tid & 63;
  const int wave = tid >> 6;
  const int n = seqlen[row];                  // 16 <= n < 8192
  const uint32_t k = (uint32_t)(n >> 4) + 1;  // 2..512, k <= n

  // conservative spill threshold: count(x >= t0) >= k with >=7 sigma margin
  const float sk = sqrtf((float)k);
  const float p0 = ((float)k + 8.0f * sk + 16.0f) / (float)n;
  const float t0 = (p0 >= 0.45f) ? -12.0f : inv_q(p0);

  hist[tid] = 0u;
  if (tid == 0) ccount = 0;
  __syncthreads();

  // ---- single sweep: predicated float4 loads, compare, spill x >= t0
  const float4* src = reinterpret_cast<const float4*>(scores + (size_t)row * SLEN);
  #pragma unroll
  for (int i = 0; i < SLEN / 4 / BLK; ++i) {
    int q4 = i * BLK + tid;                   // elems 4q4 .. 4q4+3
    if (4 * q4 < n) {
      float4 q = src[q4];
      float xs[4] = {q.x, q.y, q.z, q.w};
      #pragma unroll
      for (int c = 0; c < 4; ++c) {
        if (4 * q4 + c < n && xs[c] >= t0) {
          int idx = atomicAdd(&ccount, 1);
          if (idx < CAP) cand[idx] = xs[c];
          atomicAdd(&hist[bin_of(xs[c])], 1u);
        }
      }
    }
  }
  __syncthreads();

  const int C0 = ccount;                      // block-uniform
  float psum = 0.0f;

  if (C0 >= (int)k && C0 <= CAP) {
    // ================= FAST PATH =================
    // kth value >= t0 guaranteed (at least k spilled values >= t0), so
    // ranks among spilled == ranks among all for every spilled value.
    const uint32_t wsum = hist[tid];
    uint32_t sfx = wsum;
    #pragma unroll
    for (int d = 1; d < 64; d <<= 1) {
      uint32_t o = __shfl_down(sfx, d, 64);
      if (lane + d < 64) sfx += o;
    }
    if (lane == 0) wtot[wave] = sfx;
    __syncthreads();
    uint32_t tailw = 0;
    #pragma unroll
    for (int w = 0; w < NWAVE; ++w)
      if (w > wave) tailw += wtot[w];
    const uint32_t F = sfx + tailw;           // # spilled in bins >= tid
    const uint32_t above = F - wsum;          // # spilled in bins > tid
    if (F >= k && above < k) selBin = (uint32_t)tid;
    __syncthreads();
    const int bstar = (int)selBin;

    for (int i = tid; i < C0; i += BLK) {
      float x = cand[i];
      int b = bin_of(x);
      if (b > bstar) {
        psum += x;                            // rank < k for sure
      } else if (b == bstar) {
        uint32_t r = 0;
        for (int j = 0; j < C0; ++j) {        // LDS broadcast reads
          float y = cand[j];
          r += (uint32_t)((y > x) || (y == x && j < i));
        }
        if (r < k) psum += x;                 // exact tie-aware global rank
      }
    }
  } else {
    // ================= FALLBACK (exact; ~never taken) =================
    hist[tid] = 0u;
    if (tid == 0) ccount = 0;
    __syncthreads();
    #pragma unroll
    for (int i = 0; i < SLEN / 4 / BLK; ++i) {
      int q4 = i * BLK + tid;
      if (4 * q4 < n) {
        float4 q = src[q4];
        float xs[4] = {q.x, q.y, q.z, q.w};
        #pragma unroll
        for (int c = 0; c < 4; ++c)
          if (4 * q4 + c < n) atomicAdd(&hist[bin_of(xs[c])], 1u);
      }
    }
    __syncthreads();

    const uint32_t wsum = hist[tid];
    uint32_t sfx = wsum;
    #pragma unroll
    for (int d = 1; d < 64; d <<= 1) {
      uint32_t o = __shfl_down(sfx, d, 64);
      if (lane + d < 64) sfx += o;
    }
    if (lane == 0) wtot[wave] = sfx;
    __syncthreads();
    uint32_t tailw = 0;
    #pragma unroll
    for (int w = 0; w < NWAVE; ++w)
      if (w > wave) tailw += wtot[w];
    const uint32_t F = sfx + tailw;
    const uint32_t above = F - wsum;
    if (F >= k && above < k) { selBin = (uint32_t)tid; selAbove = above; }
    __syncthreads();
    const int bstar = (int)selBin;
    const uint32_t remaining = k - selAbove;

    #pragma unroll
    for (int i = 0; i < SLEN / 4 / BLK; ++i) {
      int q4 = i * BLK + tid;
      if (4 * q4 < n) {
        float4 q = src[q4];
        float xs[4] = {q.x, q.y, q.z, q.w};
        #pragma unroll
        for (int c = 0; c < 4; ++c) {
          if (4 * q4 + c < n) {
            float x = xs[c];
            int b = bin_of(x);
            if (b > bstar) {
              psum += x;
            } else if (b == bstar) {
              int idx = atomicAdd(&ccount, 1);
              if (idx < CAP) cand[idx] = x;
            }
          }
        }
      }
    }
    __syncthreads();
    const int C = min(ccount, CAP);
    for (int i = tid; i < C; i += BLK) {
      float x = cand[i];
      uint32_t r = 0;
      for (int j = 0; j < C; ++j) {
        float y = cand[j];
        r += (uint32_t)((y > x) || (y == x && j < i));
      }
      if (r < remaining) psum += x;
    }
  }

  // ---- block reduce, sigmoid + BCE term
  #pragma unroll
  for (int d = 32; d >= 1; d >>= 1) psum += __shfl_down(psum, d, 64);
  if (lane == 0) redbuf[wave] = psum;
  __syncthreads();
  if (tid == 0) {
    float tot = 0.0f;
    #pragma unroll
    for (int w = 0; w < NWAVE; ++w) tot += redbuf[w];
    float mean = tot / (float)k;
    float inst = 1.0f / (1.0f + expf(-mean));
    float lab = label[row];
    float term = lab * logf(inst + 1e-12f) +
                 (1.0f - lab) * logf(1.0f - inst + 1e-12f);
    rowterm[row] = term;
  }
}

__global__ __launch_bounds__(1024) void reduce_rows(
    const float* __restrict__ rowterm, float* __restrict__ out, int rows) {
  __shared__ float red[16];
  const int tid = threadIdx.x;
  const int lane = tid & 63;
  const int wave = tid >> 6;
  float s = 0.0f;
  for (int i = tid; i < rows; i += 1024) s += rowterm[i];
  #pragma unroll
  for (int d = 32; d >= 1; d >>= 1) s += __shfl_down(s, d, 64);
  if (lane == 0) red[wave] = s;
  __syncthreads();
  if (tid == 0) {
    float tot = 0.0f;
    #pragma unroll
    for (int w = 0; w < 16; ++w) tot += red[w];
    out[0] = -tot / (float)rows;
  }
}

extern "C" void kernel_launch(void* const* d_in, const int* in_sizes, int n_in,
                              void* d_out, int out_size, void* d_ws, size_t ws_size,
                              hipStream_t stream) {
  const float* scores = (const float*)d_in[0];
  const float* label  = (const float*)d_in[1];
  const int*   seqlen = (const int*)d_in[2];
  float* out = (float*)d_out;
  float* rowterm = (float*)d_ws;               // rows * 4 B scratch

  const int rows = in_sizes[1];                // B = 4096

  topk_bce_rows<<<rows, BLK, 0, stream>>>(scores, label, seqlen, rowterm);
  reduce_rows<<<1, 1024, 0, stream>>>(rowterm, out, rows);
}

// Round 7
// 358.647 us; speedup vs baseline: 1.0102x; 1.0102x over previous
//
#include <hip/hip_runtime.h>
#include <stdint.h>

// B=4096 rows, S=8192 fp32 scores. Per row: k = seqlen/16+1, mean of top-k of
// first seqlen entries, sigmoid, BCE vs label, mean over rows -> scalar.
//
// Round 7: one-pass threshold filter, fixed. Round-6 regression causes:
// (a) loads not batched (VGPR=24 -> serial load latency), (b) single-address
// LDS atomic compaction (~700-deep serialization). Now: batched predicated
// loads into v[32]; ATOMIC-FREE compaction (popcount + shuffle scan + wave
// fixup -> per-thread write base); histogram only the ~700 compacted
// candidates; suffix-scan select; exact tie-aware rank of boundary bin.
// Exact two-pass fallback from registers if filter under/overflows (~1e-15).
// ~126us of dur_us is harness reset traffic (ws poison + d_in restore).

#define SLEN 8192
#define BLK 256
#define NWAVE (BLK / 64)
#define VPT (SLEN / BLK / 4)   // 8 float4 loads per thread
#define NB 256                 // bins over [-6, 6); 1 bin per thread
#define CAP 2048
#define LOV (-6.0f)
#define SCALE (NB / 12.0f)

__device__ __forceinline__ int bin_of(float x) {
  int b = (int)((x - LOV) * SCALE);   // monotone non-decreasing in x
  return b < 0 ? 0 : (b > NB - 1 ? NB - 1 : b);
}

// Inverse upper-tail normal quantile, biased low (conservative).
// Hastings rational approx, |err| < ~5e-3, valid for p in (0, 0.5].
__device__ __forceinline__ float inv_q(float p) {
  float t = sqrtf(-2.0f * logf(p));
  return t - (2.30753f + 0.27061f * t) /
                 (1.0f + 0.99229f * t + 0.04481f * t * t) -
         0.03f;
}

__global__ __launch_bounds__(BLK, 8) void topk_bce_rows(
    const float* __restrict__ scores, const float* __restrict__ label,
    const int* __restrict__ seqlen, float* __restrict__ rowterm) {
  __shared__ float cand[CAP];        // 8 KB spill buffer
  __shared__ uint32_t hist[NB];      // 1 KB
  __shared__ uint32_t wtot[NWAVE];
  __shared__ uint32_t selBin, selAbove;
  __shared__ int ccount;             // fallback only
  __shared__ float redbuf[NWAVE];

  const int row = blockIdx.x;
  const int tid = threadIdx.x;
  const int lane = tid & 63;
  const int wave = tid >> 6;
  const int n = seqlen[row];                  // 16 <= n < 8192
  const uint32_t k = (uint32_t)(n >> 4) + 1;  // 2..512, k <= n

  // conservative spill threshold: P(count(x>=t0) >= k) ~ 1 - 1e-15
  const float sk = sqrtf((float)k);
  const float p0 = ((float)k + 8.0f * sk + 16.0f) / (float)n;
  const float t0 = (p0 >= 0.45f) ? -12.0f : inv_q(p0);

  hist[tid] = 0u;
  if (tid == 0) ccount = 0;

  // ---- batched predicated loads: 8 independent float4s -> v[32]
  const float4* src = reinterpret_cast<const float4*>(scores + (size_t)row * SLEN);
  float v[VPT * 4];
  #pragma unroll
  for (int i = 0; i < VPT; ++i) {
    int q4 = i * BLK + tid;                   // elems 4q4 .. 4q4+3
    if (4 * q4 < n) {
      float4 q = src[q4];
      v[i * 4 + 0] = q.x; v[i * 4 + 1] = q.y;
      v[i * 4 + 2] = q.z; v[i * 4 + 3] = q.w;
    }
  }

  // ---- count predicates (no memory ops)
  uint32_t cnt = 0;
  #pragma unroll
  for (int i = 0; i < VPT; ++i)
    #pragma unroll
    for (int c = 0; c < 4; ++c) {
      int pos = i * (BLK * 4) + tid * 4 + c;
      cnt += (uint32_t)(pos < n && v[i * 4 + c] >= t0);
    }

  // ---- block exclusive scan of cnt -> per-thread write base (atomic-free)
  uint32_t inc = cnt;
  #pragma unroll
  for (int d = 1; d < 64; d <<= 1) {
    uint32_t o = __shfl_up(inc, d, 64);
    if (lane >= d) inc += o;
  }
  if (lane == 63) wtot[wave] = inc;           // wave total
  __syncthreads();
  uint32_t wbase = 0, tot = 0;
  #pragma unroll
  for (int w = 0; w < NWAVE; ++w) {
    uint32_t t = wtot[w];
    if (w < wave) wbase += t;
    tot += t;
  }
  const int C0 = (int)tot;
  int base = (int)(wbase + inc - cnt);

  float psum = 0.0f;

  if (C0 >= (int)k && C0 <= CAP) {
    // ================= FAST PATH =================
    // ---- compact spilled values into cand[] (consecutive per thread)
    #pragma unroll
    for (int i = 0; i < VPT; ++i)
      #pragma unroll
      for (int c = 0; c < 4; ++c) {
        int pos = i * (BLK * 4) + tid * 4 + c;
        float x = v[i * 4 + c];
        if (pos < n && x >= t0) cand[base++] = x;
      }
    __syncthreads();

    // ---- histogram the candidates only (~3/thread, spread over tail bins)
    for (int i = tid; i < C0; i += BLK)
      atomicAdd(&hist[bin_of(cand[i])], 1u);
    __syncthreads();

    // ---- suffix scan over bins; find boundary bin b*
    const uint32_t wsum = hist[tid];
    uint32_t sfx = wsum;
    #pragma unroll
    for (int d = 1; d < 64; d <<= 1) {
      uint32_t o = __shfl_down(sfx, d, 64);
      if (lane + d < 64) sfx += o;
    }
    __syncthreads();                          // wtot reuse
    if (lane == 0) wtot[wave] = sfx;
    __syncthreads();
    uint32_t tailw = 0;
    #pragma unroll
    for (int w = 0; w < NWAVE; ++w)
      if (w > wave) tailw += wtot[w];
    const uint32_t F = sfx + tailw;           // # cands in bins >= tid
    const uint32_t above = F - wsum;          // # cands in bins > tid
    if (F >= k && above < k) selBin = (uint32_t)tid;
    __syncthreads();
    const int bstar = (int)selBin;

    // ---- sum bins > b*; exact tie-aware global rank inside b*
    for (int i = tid; i < C0; i += BLK) {
      float x = cand[i];
      int b = bin_of(x);
      if (b > bstar) {
        psum += x;
      } else if (b == bstar) {
        uint32_t r = 0;
        for (int j = 0; j < C0; ++j) {        // LDS broadcast reads
          float y = cand[j];
          r += (uint32_t)((y > x) || (y == x && j < i));
        }
        if (r < k) psum += x;                 // spilled ranks == global ranks
      }
    }
  } else {
    // ================= FALLBACK (exact; ~never taken) =================
    __syncthreads();
    hist[tid] = 0u;
    __syncthreads();
    #pragma unroll
    for (int i = 0; i < VPT; ++i)
      #pragma unroll
      for (int c = 0; c < 4; ++c) {
        int pos = i * (BLK * 4) + tid * 4 + c;
        if (pos < n) atomicAdd(&hist[bin_of(v[i * 4 + c])], 1u);
      }
    __syncthreads();

    const uint32_t wsum = hist[tid];
    uint32_t sfx = wsum;
    #pragma unroll
    for (int d = 1; d < 64; d <<= 1) {
      uint32_t o = __shfl_down(sfx, d, 64);
      if (lane + d < 64) sfx += o;
    }
    __syncthreads();
    if (lane == 0) wtot[wave] = sfx;
    __syncthreads();
    uint32_t tailw = 0;
    #pragma unroll
    for (int w = 0; w < NWAVE; ++w)
      if (w > wave) tailw += wtot[w];
    const uint32_t F = sfx + tailw;
    const uint32_t above = F - wsum;
    if (F >= k && above < k) { selBin = (uint32_t)tid; selAbove = above; }
    __syncthreads();
    const int bstar = (int)selBin;
    const uint32_t remaining = k - selAbove;

    #pragma unroll
    for (int i = 0; i < VPT; ++i)
      #pragma unroll
      for (int c = 0; c < 4; ++c) {
        int pos = i * (BLK * 4) + tid * 4 + c;
        if (pos < n) {
          float x = v[i * 4 + c];
          int b = bin_of(x);
          if (b > bstar) {
            psum += x;
          } else if (b == bstar) {
            int idx = atomicAdd(&ccount, 1);
            if (idx < CAP) cand[idx] = x;
          }
        }
      }
    __syncthreads();
    const int C = min(ccount, CAP);
    for (int i = tid; i < C; i += BLK) {
      float x = cand[i];
      uint32_t r = 0;
      for (int j = 0; j < C; ++j) {
        float y = cand[j];
        r += (uint32_t)((y > x) || (y == x && j < i));
      }
      if (r < remaining) psum += x;
    }
  }

  // ---- block reduce, sigmoid + BCE term
  #pragma unroll
  for (int d = 32; d >= 1; d >>= 1) psum += __shfl_down(psum, d, 64);
  if (lane == 0) redbuf[wave] = psum;
  __syncthreads();
  if (tid == 0) {
    float tot2 = 0.0f;
    #pragma unroll
    for (int w = 0; w < NWAVE; ++w) tot2 += redbuf[w];
    float mean = tot2 / (float)k;
    float inst = 1.0f / (1.0f + expf(-mean));
    float lab = label[row];
    float term = lab * logf(inst + 1e-12f) +
                 (1.0f - lab) * logf(1.0f - inst + 1e-12f);
    rowterm[row] = term;
  }
}

__global__ __launch_bounds__(256) void reduce_rows(
    const float* __restrict__ rowterm, float* __restrict__ out, int rows) {
  __shared__ float red[4];
  const int tid = threadIdx.x;
  const int lane = tid & 63;
  const int wave = tid >> 6;
  float s = 0.0f;
  for (int i = tid; i < rows; i += 256) s += rowterm[i];
  #pragma unroll
  for (int d = 32; d >= 1; d >>= 1) s += __shfl_down(s, d, 64);
  if (lane == 0) red[wave] = s;
  __syncthreads();
  if (tid == 0) {
    float tot = red[0] + red[1] + red[2] + red[3];
    out[0] = -tot / (float)rows;
  }
}

extern "C" void kernel_launch(void* const* d_in, const int* in_sizes, int n_in,
                              void* d_out, int out_size, void* d_ws, size_t ws_size,
                              hipStream_t stream) {
  const float* scores = (const float*)d_in[0];
  const float* label  = (const float*)d_in[1];
  const int*   seqlen = (const int*)d_in[2];
  float* out = (float*)d_out;
  float* rowterm = (float*)d_ws;               // rows * 4 B scratch

  const int rows = in_sizes[1];                // B = 4096

  topk_bce_rows<<<rows, BLK, 0, stream>>>(scores, label, seqlen, rowterm);
  reduce_rows<<<1, 256, 0, stream>>>(rowterm, out, rows);
}